// Round 1
// baseline (381.617 us; speedup 1.0000x reference)
//
#include <hip/hip_runtime.h>

#define INF_BITS 0x7F800000u

typedef float f32x4 __attribute__((ext_vector_type(4)));
typedef __bf16 bf16x8 __attribute__((ext_vector_type(8)));
typedef unsigned short u16x4 __attribute__((ext_vector_type(4)));
typedef unsigned short u16x8 __attribute__((ext_vector_type(8)));

static __device__ __forceinline__ unsigned short f2bf(float f) {
  unsigned int u = __float_as_uint(f);
  return (unsigned short)((u + 0x7FFFu + ((u >> 16) & 1u)) >> 16);  // RTNE
}

// ---- init: +inf into out's min-distance region, zero p2 (incl. padded tail) ----
__global__ void k_init(unsigned int* __restrict__ outu, float* __restrict__ p2) {
  int i = blockIdx.x * blockDim.x + threadIdx.x;
  if (i < 64000) outu[6400 + i] = INF_BITS;
  if (i < 2048) p2[i] = 0.0f;
}

// ---- proto norms: one wave per proto row (coalesced float4) ----
__global__ void k_p2(const float* __restrict__ protos, float* __restrict__ p2) {
  int wid = threadIdx.x >> 6, lane = threadIdx.x & 63;
  int p = blockIdx.x * 4 + wid;  // 500*4 = 2000 exactly
  const f32x4* row = (const f32x4*)(protos + (size_t)p * 2048);
  float s = 0.f;
  #pragma unroll
  for (int i = 0; i < 8; ++i) {
    f32x4 v = row[lane + i * 64];
    s += v.x * v.x + v.y * v.y + v.z * v.z + v.w * v.w;
  }
  #pragma unroll
  for (int off = 32; off; off >>= 1) s += __shfl_xor(s, off);
  if (lane == 0) p2[p] = s;
}

// ---- x norms: partial sums over k-chunks (deterministic, no atomics) ----
__global__ void k_x2p(const float* __restrict__ x, float* __restrict__ x2p) {
  int b = blockIdx.x, c = blockIdx.y, n = threadIdx.x;
  if (n >= 196) return;
  const float* base = x + ((size_t)b * 2048 + (size_t)c * 256) * 196 + n;
  float s = 0.f;
  #pragma unroll 8
  for (int k = 0; k < 256; ++k) { float v = base[(size_t)k * 196]; s += v * v; }
  x2p[(c * 32 + b) * 196 + n] = s;
}

__global__ void k_x2r(const float* __restrict__ x2p, float* __restrict__ x2) {
  int i = blockIdx.x * blockDim.x + threadIdx.x;
  if (i >= 6272) return;
  float s = 0.f;
  #pragma unroll
  for (int c = 0; c < 8; ++c) s += x2p[c * 6272 + i];
  x2[i] = s;
}

// ---- main: per (b, ntile, ptile): dot via MFMA, then min over n, atomicMin ----
__global__ __launch_bounds__(256) void k_main(
    const float* __restrict__ x, const float* __restrict__ protos,
    const float* __restrict__ p2, const float* __restrict__ x2,
    unsigned int* __restrict__ outu) {
  const int ptile = blockIdx.x;  // 16 -> p0 = ptile*128 (2048 padded)
  const int ntile = blockIdx.y;  // 4  -> n0 = ntile*64  (256 padded)
  const int b     = blockIdx.z;  // 32
  const int p0 = ptile * 128;
  const int n0 = ntile * 64;
  const int tid = threadIdx.x;

  // Ps: [p][k] bf16, stride 72 (144B = 9*16 -> b128-aligned, conflict-spread)
  // Xs: [n][k] bf16, stride 68 (136B -> 8B-aligned, conflict-spread)
  __shared__ unsigned short Ps[128][72];
  __shared__ unsigned short Xs[64][68];

  const int lane = tid & 63;
  const int w    = tid >> 6;   // wave 0..3 -> p sub-range of 32
  const int lr   = lane & 15;
  const int lg   = lane >> 4;

  f32x4 acc[2][4];
  #pragma unroll
  for (int mi = 0; mi < 2; ++mi)
    #pragma unroll
    for (int ni = 0; ni < 4; ++ni)
      acc[mi][ni] = (f32x4){0.f, 0.f, 0.f, 0.f};

  const int tk = tid & 15;   // *4 element offset
  const int tr = tid >> 4;   // 0..15
  const float* xb = x + (size_t)b * 2048 * 196;  // x[b][k][n]

  for (int kt = 0; kt < 32; ++kt) {
    const int k0 = kt * 64;
    __syncthreads();
    // stage protos 128 x 64 (rows k-contiguous in global)
    #pragma unroll
    for (int r = 0; r < 8; ++r) {
      const int row = r * 16 + tr;
      const int p = p0 + row;
      f32x4 v = (f32x4){0.f, 0.f, 0.f, 0.f};
      if (p < 2000) v = *(const f32x4*)(protos + (size_t)p * 2048 + k0 + tk * 4);
      u16x4 h = { f2bf(v.x), f2bf(v.y), f2bf(v.z), f2bf(v.w) };
      *(u16x4*)&Ps[row][tk * 4] = h;
    }
    // stage x 64k x 64n with transpose (global rows n-contiguous)
    #pragma unroll
    for (int r = 0; r < 4; ++r) {
      const int kl = r * 16 + tr;
      const float* src = xb + (size_t)(k0 + kl) * 196 + n0 + tk * 4;
      float v0, v1, v2, v3;
      if (n0 + tk * 4 + 3 < 196) {
        f32x4 v = *(const f32x4*)src;
        v0 = v.x; v1 = v.y; v2 = v.z; v3 = v.w;
      } else {
        v0 = (n0 + tk * 4 + 0 < 196) ? src[0] : 0.f;
        v1 = (n0 + tk * 4 + 1 < 196) ? src[1] : 0.f;
        v2 = (n0 + tk * 4 + 2 < 196) ? src[2] : 0.f;
        v3 = (n0 + tk * 4 + 3 < 196) ? src[3] : 0.f;
      }
      Xs[tk * 4 + 0][kl] = f2bf(v0);
      Xs[tk * 4 + 1][kl] = f2bf(v1);
      Xs[tk * 4 + 2][kl] = f2bf(v2);
      Xs[tk * 4 + 3][kl] = f2bf(v3);
    }
    __syncthreads();
    // MFMA: A = protos (M), B = x (N); both frags k-contiguous, same k-convention
    #pragma unroll
    for (int ks = 0; ks < 2; ++ks) {
      bf16x8 af[2];
      #pragma unroll
      for (int mi = 0; mi < 2; ++mi) {
        u16x8 u = *(const u16x8*)&Ps[w * 32 + mi * 16 + lr][ks * 32 + 8 * lg];
        af[mi] = __builtin_bit_cast(bf16x8, u);
      }
      bf16x8 bfv[4];
      #pragma unroll
      for (int ni = 0; ni < 4; ++ni) {
        u16x4 a0 = *(const u16x4*)&Xs[ni * 16 + lr][ks * 32 + 8 * lg];
        u16x4 a1 = *(const u16x4*)&Xs[ni * 16 + lr][ks * 32 + 8 * lg + 4];
        u16x8 u = __builtin_shufflevector(a0, a1, 0, 1, 2, 3, 4, 5, 6, 7);
        bfv[ni] = __builtin_bit_cast(bf16x8, u);
      }
      #pragma unroll
      for (int mi = 0; mi < 2; ++mi)
        #pragma unroll
        for (int ni = 0; ni < 4; ++ni)
          acc[mi][ni] = __builtin_amdgcn_mfma_f32_16x16x32_bf16(
              af[mi], bfv[ni], acc[mi][ni], 0, 0, 0);
    }
  }

  // epilogue: d2 = x2[n] + p2[p] - 2*dot ; min over the block's 64 n ; atomicMin
  float x2v[4];
  #pragma unroll
  for (int ni = 0; ni < 4; ++ni) {
    const int n = n0 + ni * 16 + lr;  // D col = lane&15
    x2v[ni] = (n < 196) ? x2[b * 196 + n] : __uint_as_float(INF_BITS);
  }
  #pragma unroll
  for (int mi = 0; mi < 2; ++mi) {
    const int prow = p0 + w * 32 + mi * 16 + 4 * lg;  // D row = 4*(lane>>4)+j
    #pragma unroll
    for (int j = 0; j < 4; ++j) {
      const int p = prow + j;
      const float pp = p2[p];
      float m = __uint_as_float(INF_BITS);
      #pragma unroll
      for (int ni = 0; ni < 4; ++ni) {
        const float d2 = x2v[ni] + pp - 2.f * acc[mi][ni][j];
        m = fminf(m, d2);
      }
      m = fminf(m, __shfl_xor(m, 1));
      m = fminf(m, __shfl_xor(m, 2));
      m = fminf(m, __shfl_xor(m, 4));
      m = fminf(m, __shfl_xor(m, 8));
      if (lr == 0 && p < 2000)
        atomicMin(&outu[6400 + b * 2000 + p], __float_as_uint(fmaxf(m, 0.f)));
    }
  }
}

// ---- final: d = sqrt(max(d2,1e-12)) in place; scores = sim @ fc_w^T ----
__global__ void k_final(const float* __restrict__ fc_w, float* __restrict__ out) {
  const int b = blockIdx.x;
  const int tid = threadIdx.x;
  __shared__ float sim[2000];
  for (int p = tid; p < 2000; p += 256) {
    float d2 = out[6400 + b * 2000 + p];
    float d = sqrtf(fmaxf(d2, 1e-12f));
    out[6400 + b * 2000 + p] = d;
    sim[p] = logf((d + 1.0f) / (d + 1e-7f));
  }
  __syncthreads();
  if (tid < 200) {
    const f32x4* wr = (const f32x4*)(fc_w + (size_t)tid * 2000);
    float s = 0.f;
    #pragma unroll 4
    for (int i = 0; i < 500; ++i) {
      f32x4 wv = wr[i];
      const float* sp = &sim[i * 4];
      s += wv.x * sp[0] + wv.y * sp[1] + wv.z * sp[2] + wv.w * sp[3];
    }
    out[b * 200 + tid] = s;
  }
}

extern "C" void kernel_launch(void* const* d_in, const int* in_sizes, int n_in,
                              void* d_out, int out_size, void* d_ws, size_t ws_size,
                              hipStream_t stream) {
  const float* x      = (const float*)d_in[0];  // (32, 2048, 14, 14) f32
  const float* protos = (const float*)d_in[1];  // (1, 2000, 2048) f32
  const float* fc_w   = (const float*)d_in[2];  // (200, 2000) f32
  float* out = (float*)d_out;                   // 6400 scores + 64000 min-dists
  float* ws  = (float*)d_ws;
  float* p2  = ws;          // 2048 floats
  float* x2  = ws + 2048;   // 6272 floats
  float* x2p = ws + 8320;   // 8*6272 floats (total ~234 KB)

  k_init<<<250, 256, 0, stream>>>((unsigned int*)d_out, p2);
  k_p2<<<500, 256, 0, stream>>>(protos, p2);
  k_x2p<<<dim3(32, 8), 256, 0, stream>>>(x, x2p);
  k_x2r<<<25, 256, 0, stream>>>(x2p, x2);
  k_main<<<dim3(16, 4, 32), 256, 0, stream>>>(x, protos, p2, x2,
                                              (unsigned int*)d_out);
  k_final<<<32, 256, 0, stream>>>(fc_w, out);
}

// Round 2
// 189.443 us; speedup vs baseline: 2.0144x; 2.0144x over previous
//
#include <hip/hip_runtime.h>

#define INF_BITS 0x7F800000u

typedef float f32x4 __attribute__((ext_vector_type(4)));
typedef __bf16 bf16x8 __attribute__((ext_vector_type(8)));
typedef unsigned short u16x8 __attribute__((ext_vector_type(8)));

static __device__ __forceinline__ unsigned short f2bf(float f) {
  unsigned int u = __float_as_uint(f);
  return (unsigned short)((u + 0x7FFFu + ((u >> 16) & 1u)) >> 16);  // RTNE
}

// ---- init: +inf into out's min-distance region ----
__global__ void k_init(unsigned int* __restrict__ outu) {
  int i = blockIdx.x * blockDim.x + threadIdx.x;
  if (i < 64000) outu[6400 + i] = INF_BITS;
}

// ---- protos (2000x2048 f32) -> pT (2048x2048 bf16, pad rows zero) + p2 ----
__global__ __launch_bounds__(256) void k_prep_p(const float* __restrict__ protos,
                                                unsigned short* __restrict__ pT,
                                                float* __restrict__ p2) {
  const int row = blockIdx.x;   // 2048
  const int tid = threadIdx.x;  // 256
  __shared__ float red[4];
  float s = 0.f;
  u16x8 h = (u16x8){0, 0, 0, 0, 0, 0, 0, 0};
  if (row < 2000) {
    const float* src = protos + (size_t)row * 2048 + tid * 8;
    f32x4 a = *(const f32x4*)src;
    f32x4 c = *(const f32x4*)(src + 4);
    h = (u16x8){f2bf(a.x), f2bf(a.y), f2bf(a.z), f2bf(a.w),
                f2bf(c.x), f2bf(c.y), f2bf(c.z), f2bf(c.w)};
    s = a.x * a.x + a.y * a.y + a.z * a.z + a.w * a.w +
        c.x * c.x + c.y * c.y + c.z * c.z + c.w * c.w;
  }
  *(u16x8*)(pT + (size_t)row * 2048 + tid * 8) = h;
  #pragma unroll
  for (int off = 32; off; off >>= 1) s += __shfl_xor(s, off);
  if ((tid & 63) == 0) red[tid >> 6] = s;
  __syncthreads();
  if (tid == 0) p2[row] = red[0] + red[1] + red[2] + red[3];
}

// ---- x (b,k,n) f32 -> xT[(b*196+n)*2048 + k] bf16 (LDS-tiled transpose) ----
__global__ __launch_bounds__(256) void k_prep_x(const float* __restrict__ x,
                                                unsigned short* __restrict__ xT) {
  const int kt = blockIdx.x;  // 32
  const int b  = blockIdx.y;  // 32
  const int tid = threadIdx.x;
  __shared__ unsigned short Ls[64][201];
  const float* src = x + (size_t)b * 2048 * 196 + (size_t)kt * 64 * 196;
  for (int idx = tid; idx < 64 * 196; idx += 256) {
    int kk = idx / 196, n = idx - kk * 196;
    Ls[kk][n] = f2bf(src[idx]);
  }
  __syncthreads();
  unsigned short* dstb = xT + (size_t)b * 196 * 2048 + kt * 64;
  for (int idx = tid; idx < 196 * 32; idx += 256) {
    int n = idx >> 5, j = idx & 31;
    unsigned int v = (unsigned int)Ls[2 * j][n] |
                     ((unsigned int)Ls[2 * j + 1][n] << 16);
    *(unsigned int*)(dstb + (size_t)n * 2048 + 2 * j) = v;
  }
}

// ---- x norms: partial sums over k-chunks (deterministic) ----
__global__ void k_x2p(const float* __restrict__ x, float* __restrict__ x2p) {
  int b = blockIdx.x, c = blockIdx.y, n = threadIdx.x;
  if (n >= 196) return;
  const float* base = x + ((size_t)b * 2048 + (size_t)c * 256) * 196 + n;
  float s = 0.f;
  #pragma unroll 8
  for (int k = 0; k < 256; ++k) { float v = base[(size_t)k * 196]; s += v * v; }
  x2p[(c * 32 + b) * 196 + n] = s;
}

__global__ void k_x2r(const float* __restrict__ x2p, float* __restrict__ x2) {
  int i = blockIdx.x * blockDim.x + threadIdx.x;
  if (i >= 6272) return;
  float s = 0.f;
  #pragma unroll
  for (int c = 0; c < 8; ++c) s += x2p[c * 6272 + i];
  x2[i] = s;
}

// ---- main GEMM: A = pT (p rows), B = xT (m rows), K = 2048, 128x128 tile ----
// m97 structure: global_load_lds(16B) with pre-swizzled source, XOR-swizzled
// ds_read_b128 fragments (chunk ^= row&7 involution), 2 barriers per K-step.
__global__ __launch_bounds__(256) void k_main(
    const unsigned short* __restrict__ pT, const unsigned short* __restrict__ xT,
    const float* __restrict__ p2, const float* __restrict__ x2,
    unsigned int* __restrict__ outu) {
  const int ptile = blockIdx.x;  // 16
  const int mtile = blockIdx.y;  // 49
  const int p0 = ptile * 128;
  const int m0 = mtile * 128;
  const int tid = threadIdx.x;
  const int lane = tid & 63;
  const int w = tid >> 6;      // 4 waves
  const int wp = w >> 1;       // p half (64)
  const int wm = w & 1;        // m half (64)
  const int lr = lane & 15;
  const int lg = lane >> 4;

  __shared__ __align__(16) char As[16384];  // [128 rows][128 B], swizzled
  __shared__ __align__(16) char Bs[16384];

  f32x4 acc[4][4];
  #pragma unroll
  for (int mi = 0; mi < 4; ++mi)
    #pragma unroll
    for (int ni = 0; ni < 4; ++ni)
      acc[mi][ni] = (f32x4){0.f, 0.f, 0.f, 0.f};

  // staging source addresses (pre-swizzled: chunk ^= row&7, row&7 == lane>>3)
  const int lrow = lane >> 3;                    // 0..7
  const int chunk = (lane & 7) ^ lrow;           // involution
  const size_t soff = (size_t)((w * 8 + lrow) * 4096 + chunk * 16);
  const char* srcA0 = (const char*)pT + (size_t)p0 * 4096 + soff;
  const char* srcB0 = (const char*)xT + (size_t)m0 * 4096 + soff;
  char* dstA0 = As + w * 1024;
  char* dstB0 = Bs + w * 1024;

  const int swz = (lr & 7) << 4;

  for (int kt = 0; kt < 32; ++kt) {
    __syncthreads();  // previous iter's reads done
    const size_t kadd = (size_t)kt * 128;
    #pragma unroll
    for (int i = 0; i < 4; ++i) {
      __builtin_amdgcn_global_load_lds(
          (const __attribute__((address_space(1))) void*)(srcA0 + (size_t)i * 131072 + kadd),
          (__attribute__((address_space(3))) void*)(dstA0 + i * 4096), 16, 0, 0);
      __builtin_amdgcn_global_load_lds(
          (const __attribute__((address_space(1))) void*)(srcB0 + (size_t)i * 131072 + kadd),
          (__attribute__((address_space(3))) void*)(dstB0 + i * 4096), 16, 0, 0);
    }
    __syncthreads();  // vmcnt drain + visibility

    #pragma unroll
    for (int ks = 0; ks < 2; ++ks) {
      bf16x8 af[4], bfv[4];
      #pragma unroll
      for (int mi = 0; mi < 4; ++mi) {
        int row = wp * 64 + mi * 16 + lr;
        int off = row * 128 + ((ks * 64 + lg * 16) ^ swz);
        af[mi] = *(const bf16x8*)(As + off);
      }
      #pragma unroll
      for (int ni = 0; ni < 4; ++ni) {
        int row = wm * 64 + ni * 16 + lr;
        int off = row * 128 + ((ks * 64 + lg * 16) ^ swz);
        bfv[ni] = *(const bf16x8*)(Bs + off);
      }
      #pragma unroll
      for (int mi = 0; mi < 4; ++mi)
        #pragma unroll
        for (int ni = 0; ni < 4; ++ni)
          acc[mi][ni] = __builtin_amdgcn_mfma_f32_16x16x32_bf16(
              af[mi], bfv[ni], acc[mi][ni], 0, 0, 0);
    }
  }

  // epilogue: d2 = x2[m] + p2[p] - 2*dot ; segmented min over m (<=2 batches)
  const int m_base = m0 + wm * 64;
  const int b_lo = m0 / 196;
  const int b_hi = (m0 + 127) / 196;
  float x2v[4];
  int seg0[4];
  #pragma unroll
  for (int ni = 0; ni < 4; ++ni) {
    const int m = m_base + ni * 16 + lr;  // D col = lane&15
    x2v[ni] = x2[m];
    seg0[ni] = ((m / 196) == b_lo);
  }
  const float INF = __uint_as_float(INF_BITS);
  #pragma unroll
  for (int mi = 0; mi < 4; ++mi) {
    const int prow = p0 + wp * 64 + mi * 16 + 4 * lg;  // D row = 4*(lane>>4)+j
    #pragma unroll
    for (int j = 0; j < 4; ++j) {
      const int p = prow + j;
      const float pp = p2[p];
      float ma = INF, mb = INF;
      #pragma unroll
      for (int ni = 0; ni < 4; ++ni) {
        const float d2 = x2v[ni] + pp - 2.f * acc[mi][ni][j];
        ma = fminf(ma, seg0[ni] ? d2 : INF);
        mb = fminf(mb, seg0[ni] ? INF : d2);
      }
      #pragma unroll
      for (int off = 1; off < 16; off <<= 1) {
        ma = fminf(ma, __shfl_xor(ma, off));
        mb = fminf(mb, __shfl_xor(mb, off));
      }
      if (lr == 0 && p < 2000) {
        atomicMin(&outu[6400 + b_lo * 2000 + p], __float_as_uint(fmaxf(ma, 0.f)));
        if (b_hi != b_lo)
          atomicMin(&outu[6400 + b_hi * 2000 + p], __float_as_uint(fmaxf(mb, 0.f)));
      }
    }
  }
}

// ---- final: d = sqrt(max(d2,1e-12)) in place; scores = sim @ fc_w^T ----
__global__ void k_final(const float* __restrict__ fc_w, float* __restrict__ out) {
  const int b = blockIdx.x;
  const int tid = threadIdx.x;
  __shared__ float sim[2000];
  for (int p = tid; p < 2000; p += 256) {
    float d2 = out[6400 + b * 2000 + p];
    float d = sqrtf(fmaxf(d2, 1e-12f));
    out[6400 + b * 2000 + p] = d;
    sim[p] = logf((d + 1.0f) / (d + 1e-7f));
  }
  __syncthreads();
  if (tid < 200) {
    const f32x4* wr = (const f32x4*)(fc_w + (size_t)tid * 2000);
    float s = 0.f;
    #pragma unroll 4
    for (int i = 0; i < 500; ++i) {
      f32x4 wv = wr[i];
      const float* sp = &sim[i * 4];
      s += wv.x * sp[0] + wv.y * sp[1] + wv.z * sp[2] + wv.w * sp[3];
    }
    out[b * 200 + tid] = s;
  }
}

extern "C" void kernel_launch(void* const* d_in, const int* in_sizes, int n_in,
                              void* d_out, int out_size, void* d_ws, size_t ws_size,
                              hipStream_t stream) {
  const float* x      = (const float*)d_in[0];  // (32, 2048, 14, 14) f32
  const float* protos = (const float*)d_in[1];  // (1, 2000, 2048) f32
  const float* fc_w   = (const float*)d_in[2];  // (200, 2000) f32
  float* out = (float*)d_out;                   // 6400 scores + 64000 min-dists

  char* wsb = (char*)d_ws;
  unsigned short* pT = (unsigned short*)wsb;                // 2048*2048*2 = 8388608 B
  unsigned short* xT = (unsigned short*)(wsb + 8388608);    // 6272*2048*2 = 25690112 B
  float* p2  = (float*)(wsb + 34078720);                    // 2048 f32
  float* x2  = (float*)(wsb + 34086912);                    // 6272 f32
  float* x2p = (float*)(wsb + 34112000);                    // 8*6272 f32  (end ~34.3 MB)

  k_init<<<250, 256, 0, stream>>>((unsigned int*)d_out);
  k_prep_p<<<2048, 256, 0, stream>>>(protos, pT, p2);
  k_prep_x<<<dim3(32, 32), 256, 0, stream>>>(x, xT);
  k_x2p<<<dim3(32, 8), 256, 0, stream>>>(x, x2p);
  k_x2r<<<25, 256, 0, stream>>>(x2p, x2);
  k_main<<<dim3(16, 49), 256, 0, stream>>>(pT, xT, p2, x2, (unsigned int*)d_out);
  k_final<<<32, 256, 0, stream>>>(fc_w, out);
}

// Round 3
// 167.175 us; speedup vs baseline: 2.2827x; 1.1332x over previous
//
#include <hip/hip_runtime.h>

#define INF_BITS 0x7F800000u

typedef float f32x4 __attribute__((ext_vector_type(4)));
typedef __bf16 bf16x8 __attribute__((ext_vector_type(8)));
typedef unsigned short u16x8 __attribute__((ext_vector_type(8)));
typedef unsigned int u32x4 __attribute__((ext_vector_type(4)));

static __device__ __forceinline__ unsigned short f2bf(float f) {
  unsigned int u = __float_as_uint(f);
  return (unsigned short)((u + 0x7FFFu + ((u >> 16) & 1u)) >> 16);  // RTNE
}

// ---- init: +inf into out's min-distance region ----
__global__ void k_init(unsigned int* __restrict__ outu) {
  int i = blockIdx.x * blockDim.x + threadIdx.x;
  if (i < 64000) outu[6400 + i] = INF_BITS;
}

// ---- protos (2000x2048 f32) -> pT (2048x2048 bf16, pad rows zero) + p2 ----
__global__ __launch_bounds__(256) void k_prep_p(const float* __restrict__ protos,
                                                unsigned short* __restrict__ pT,
                                                float* __restrict__ p2) {
  const int row = blockIdx.x;   // 2048
  const int tid = threadIdx.x;  // 256
  __shared__ float red[4];
  float s = 0.f;
  u16x8 h = (u16x8){0, 0, 0, 0, 0, 0, 0, 0};
  if (row < 2000) {
    const float* src = protos + (size_t)row * 2048 + tid * 8;
    f32x4 a = *(const f32x4*)src;
    f32x4 c = *(const f32x4*)(src + 4);
    h = (u16x8){f2bf(a.x), f2bf(a.y), f2bf(a.z), f2bf(a.w),
                f2bf(c.x), f2bf(c.y), f2bf(c.z), f2bf(c.w)};
    s = a.x * a.x + a.y * a.y + a.z * a.z + a.w * a.w +
        c.x * c.x + c.y * c.y + c.z * c.z + c.w * c.w;
  }
  *(u16x8*)(pT + (size_t)row * 2048 + tid * 8) = h;
  #pragma unroll
  for (int off = 32; off; off >>= 1) s += __shfl_xor(s, off);
  if ((tid & 63) == 0) red[tid >> 6] = s;
  __syncthreads();
  if (tid == 0) p2[row] = red[0] + red[1] + red[2] + red[3];
}

// ---- x (b,k,n) f32 -> xT[(b*196+n)*2048+k] bf16, fused x2 partials ----
__global__ __launch_bounds__(256) void k_prep_x(const float* __restrict__ x,
                                                unsigned short* __restrict__ xT,
                                                float* __restrict__ x2p) {
  const int kt = blockIdx.x;  // 32
  const int b  = blockIdx.y;  // 32
  const int tid = threadIdx.x;
  __shared__ unsigned short Ls[64][201];
  const float* src = x + ((size_t)b * 2048 + (size_t)kt * 64) * 196;
  for (int idx = tid; idx < 64 * 196; idx += 256) {
    int kk = idx / 196, n = idx - kk * 196;
    Ls[kk][n] = f2bf(src[idx]);
  }
  __syncthreads();
  if (tid < 196) {
    const int n = tid;
    float s = 0.f;
    unsigned int buf[32];
    #pragma unroll
    for (int j = 0; j < 32; ++j) {
      unsigned int a = Ls[2 * j][n], c = Ls[2 * j + 1][n];
      float fa = __uint_as_float(a << 16), fc = __uint_as_float(c << 16);
      s += fa * fa + fc * fc;
      buf[j] = a | (c << 16);
    }
    u32x4* dst = (u32x4*)((char*)xT + (size_t)(b * 196 + n) * 4096 + kt * 128);
    #pragma unroll
    for (int j = 0; j < 8; ++j)
      dst[j] = (u32x4){buf[4 * j], buf[4 * j + 1], buf[4 * j + 2], buf[4 * j + 3]};
    x2p[kt * 6272 + b * 196 + n] = s;
  }
}

__global__ void k_x2r(const float* __restrict__ x2p, float* __restrict__ x2) {
  int i = blockIdx.x * blockDim.x + threadIdx.x;
  if (i >= 6272) return;
  float s = 0.f;
  #pragma unroll
  for (int c = 0; c < 32; ++c) s += x2p[c * 6272 + i];
  x2[i] = s;
}

// ---- main GEMM: 128x128 tile, BK=64, depth-2 counted-vmcnt pipeline ----
__global__ __launch_bounds__(256, 2) void k_main(
    const unsigned short* __restrict__ pT, const unsigned short* __restrict__ xT,
    const float* __restrict__ p2, const float* __restrict__ x2,
    unsigned int* __restrict__ outu) {
  // XCD-chunked bijective swizzle: 784 = 8 * 98
  const int orig = blockIdx.x;
  const int wgid = (orig & 7) * 98 + (orig >> 3);
  const int ptile = wgid / 49;
  const int mtile = wgid - ptile * 49;
  const int p0 = ptile * 128;
  const int m0 = mtile * 128;
  const int tid = threadIdx.x;
  const int lane = tid & 63;
  const int w = tid >> 6;      // 4 waves
  const int wp = w >> 1;       // p half (64)
  const int wm = w & 1;        // m half (64)
  const int lr = lane & 15;
  const int lg = lane >> 4;

  __shared__ __align__(16) char LA[2][16384];  // [128 rows][128 B] swizzled
  __shared__ __align__(16) char LB[2][16384];

  f32x4 acc[4][4];
  #pragma unroll
  for (int mi = 0; mi < 4; ++mi)
    #pragma unroll
    for (int ni = 0; ni < 4; ++ni)
      acc[mi][ni] = (f32x4){0.f, 0.f, 0.f, 0.f};

  // staging: dest linear (lane*16 implicit), source pre-swizzled chunk^=row&7
  const int lrow = lane >> 3;
  const int sch = (lane & 7) ^ lrow;
  const char* gA = (const char*)pT + (size_t)(p0 + w * 8 + lrow) * 4096 + sch * 16;
  const char* gB = (const char*)xT + (size_t)(m0 + w * 8 + lrow) * 4096 + sch * 16;

#define STAGE(kt_, c_) do {                                                      \
    const size_t kb_ = (size_t)(kt_) * 128;                                      \
    _Pragma("unroll")                                                            \
    for (int i_ = 0; i_ < 4; ++i_) {                                             \
      __builtin_amdgcn_global_load_lds(                                          \
        (const __attribute__((address_space(1))) void*)(gA + (size_t)i_ * 131072 + kb_), \
        (__attribute__((address_space(3))) void*)(&LA[c_][i_ * 4096 + w * 1024]), 16, 0, 0); \
      __builtin_amdgcn_global_load_lds(                                          \
        (const __attribute__((address_space(1))) void*)(gB + (size_t)i_ * 131072 + kb_), \
        (__attribute__((address_space(3))) void*)(&LB[c_][i_ * 4096 + w * 1024]), 16, 0, 0); \
    } } while (0)

  STAGE(0, 0);
  STAGE(1, 1);
  // outstanding: 16 loads (kt0 oldest 8, kt1 newest 8)

  const int swz = (lr & 7) << 4;

  #pragma unroll 1
  for (int kt = 0; kt < 32; ++kt) {
    const int c = kt & 1;
    // arrival of kt's 8 loads (kt+1's 8 stay in flight; last iter drains all)
    if (kt == 31) asm volatile("s_waitcnt vmcnt(0)" ::: "memory");
    else          asm volatile("s_waitcnt vmcnt(8)" ::: "memory");
    __builtin_amdgcn_sched_barrier(0);
    __builtin_amdgcn_s_barrier();   // all waves: kt data visible
    __builtin_amdgcn_sched_barrier(0);

    const char* La = LA[c];
    const char* Lb = LB[c];
    bf16x8 a0[4], b0[4], a1[4], b1[4];
    #pragma unroll
    for (int mi = 0; mi < 4; ++mi) {
      int row = wp * 64 + mi * 16 + lr;
      a0[mi] = *(const bf16x8*)(La + row * 128 + ((lg * 16) ^ swz));
    }
    #pragma unroll
    for (int ni = 0; ni < 4; ++ni) {
      int row = wm * 64 + ni * 16 + lr;
      b0[ni] = *(const bf16x8*)(Lb + row * 128 + ((lg * 16) ^ swz));
    }
    __builtin_amdgcn_s_setprio(1);
    #pragma unroll
    for (int mi = 0; mi < 4; ++mi)
      #pragma unroll
      for (int ni = 0; ni < 4; ++ni)
        acc[mi][ni] = __builtin_amdgcn_mfma_f32_16x16x32_bf16(
            a0[mi], b0[ni], acc[mi][ni], 0, 0, 0);
    __builtin_amdgcn_s_setprio(0);
    #pragma unroll
    for (int mi = 0; mi < 4; ++mi) {
      int row = wp * 64 + mi * 16 + lr;
      a1[mi] = *(const bf16x8*)(La + row * 128 + ((64 + lg * 16) ^ swz));
    }
    #pragma unroll
    for (int ni = 0; ni < 4; ++ni) {
      int row = wm * 64 + ni * 16 + lr;
      b1[ni] = *(const bf16x8*)(Lb + row * 128 + ((64 + lg * 16) ^ swz));
    }
    // all ds_reads of buf c complete BEFORE releasing it for overwrite
    asm volatile("s_waitcnt lgkmcnt(0)" ::: "memory");
    __builtin_amdgcn_sched_barrier(0);
    __builtin_amdgcn_s_barrier();   // buf c free
    __builtin_amdgcn_sched_barrier(0);
    if (kt < 30) STAGE(kt + 2, c);
    __builtin_amdgcn_s_setprio(1);
    #pragma unroll
    for (int mi = 0; mi < 4; ++mi)
      #pragma unroll
      for (int ni = 0; ni < 4; ++ni)
        acc[mi][ni] = __builtin_amdgcn_mfma_f32_16x16x32_bf16(
            a1[mi], b1[ni], acc[mi][ni], 0, 0, 0);
    __builtin_amdgcn_s_setprio(0);
  }
#undef STAGE

  // epilogue: d2 = x2[m] + p2[p] - 2*dot ; segmented min over m (<=2 batches)
  const int m_base = m0 + wm * 64;
  const int b_lo = m0 / 196;
  const int b_hi = (m0 + 127) / 196;
  float x2v[4];
  int seg0[4];
  #pragma unroll
  for (int ni = 0; ni < 4; ++ni) {
    const int m = m_base + ni * 16 + lr;  // D col = lane&15
    x2v[ni] = x2[m];
    seg0[ni] = ((m / 196) == b_lo);
  }
  const float INF = __uint_as_float(INF_BITS);
  #pragma unroll
  for (int mi = 0; mi < 4; ++mi) {
    const int prow = p0 + wp * 64 + mi * 16 + 4 * lg;  // D row = 4*(lane>>4)+j
    #pragma unroll
    for (int j = 0; j < 4; ++j) {
      const int p = prow + j;
      const float pp = p2[p];
      float ma = INF, mb = INF;
      #pragma unroll
      for (int ni = 0; ni < 4; ++ni) {
        const float d2 = x2v[ni] + pp - 2.f * acc[mi][ni][j];
        ma = fminf(ma, seg0[ni] ? d2 : INF);
        mb = fminf(mb, seg0[ni] ? INF : d2);
      }
      #pragma unroll
      for (int off = 1; off < 16; off <<= 1) {
        ma = fminf(ma, __shfl_xor(ma, off));
        mb = fminf(mb, __shfl_xor(mb, off));
      }
      if (lr == 0 && p < 2000) {
        atomicMin(&outu[6400 + b_lo * 2000 + p], __float_as_uint(fmaxf(ma, 0.f)));
        if (b_hi != b_lo)
          atomicMin(&outu[6400 + b_hi * 2000 + p], __float_as_uint(fmaxf(mb, 0.f)));
      }
    }
  }
}

// ---- final: d = sqrt(max(d2,1e-12)) in place; scores = sim @ fc_w^T ----
__global__ void k_final(const float* __restrict__ fc_w, float* __restrict__ out) {
  const int b = blockIdx.x;
  const int tid = threadIdx.x;
  __shared__ float sim[2000];
  for (int p = tid; p < 2000; p += 256) {
    float d2 = out[6400 + b * 2000 + p];
    float d = sqrtf(fmaxf(d2, 1e-12f));
    out[6400 + b * 2000 + p] = d;
    sim[p] = logf((d + 1.0f) / (d + 1e-7f));
  }
  __syncthreads();
  if (tid < 200) {
    const f32x4* wr = (const f32x4*)(fc_w + (size_t)tid * 2000);
    float s = 0.f;
    #pragma unroll 4
    for (int i = 0; i < 500; ++i) {
      f32x4 wv = wr[i];
      const float* sp = &sim[i * 4];
      s += wv.x * sp[0] + wv.y * sp[1] + wv.z * sp[2] + wv.w * sp[3];
    }
    out[b * 200 + tid] = s;
  }
}

extern "C" void kernel_launch(void* const* d_in, const int* in_sizes, int n_in,
                              void* d_out, int out_size, void* d_ws, size_t ws_size,
                              hipStream_t stream) {
  const float* x      = (const float*)d_in[0];  // (32, 2048, 14, 14) f32
  const float* protos = (const float*)d_in[1];  // (1, 2000, 2048) f32
  const float* fc_w   = (const float*)d_in[2];  // (200, 2000) f32
  float* out = (float*)d_out;                   // 6400 scores + 64000 min-dists

  char* wsb = (char*)d_ws;
  unsigned short* pT = (unsigned short*)wsb;                // 2048*2048*2 = 8388608 B
  unsigned short* xT = (unsigned short*)(wsb + 8388608);    // 6272*2048*2 = 25690112 B
  float* p2  = (float*)(wsb + 34078720);                    // 2048 f32
  float* x2  = (float*)(wsb + 34086912);                    // 6272 f32
  float* x2p = (float*)(wsb + 34112000);                    // 32*6272 f32 (end ~34.9 MB)

  k_init<<<250, 256, 0, stream>>>((unsigned int*)d_out);
  k_prep_p<<<2048, 256, 0, stream>>>(protos, pT, p2);
  k_prep_x<<<dim3(32, 32), 256, 0, stream>>>(x, xT, x2p);
  k_x2r<<<25, 256, 0, stream>>>(x2p, x2);
  k_main<<<784, 256, 0, stream>>>(pT, xT, p2, x2, (unsigned int*)d_out);
  k_final<<<32, 256, 0, stream>>>(fc_w, out);
}

// Round 4
// 138.981 us; speedup vs baseline: 2.7458x; 1.2029x over previous
//
#include <hip/hip_runtime.h>

#define INF_BITS 0x7F800000u
#define AS1 __attribute__((address_space(1)))
#define AS3 __attribute__((address_space(3)))

typedef float f32x4 __attribute__((ext_vector_type(4)));
typedef __bf16 bf16x8 __attribute__((ext_vector_type(8)));
typedef unsigned short u16x8 __attribute__((ext_vector_type(8)));
typedef unsigned int u32x4 __attribute__((ext_vector_type(4)));

static __device__ __forceinline__ unsigned short f2bf(float f) {
  unsigned int u = __float_as_uint(f);
  return (unsigned short)((u + 0x7FFFu + ((u >> 16) & 1u)) >> 16);  // RTNE
}

// ---- init: +inf min-dists; zero xT pad rows; +inf x2 pad ----
__global__ void k_init(unsigned int* __restrict__ outu, u32x4* __restrict__ xTpad,
                       unsigned int* __restrict__ x2u) {
  int i = blockIdx.x * blockDim.x + threadIdx.x;
  if (i < 64000) outu[6400 + i] = INF_BITS;
  if (i < 32768) xTpad[i] = (u32x4){0u, 0u, 0u, 0u};  // rows 6272..6399 of xT
  if (i < 128) x2u[6272 + i] = INF_BITS;
}

// ---- protos (2000x2048 f32) -> pT (2048x2048 bf16, pad rows zero) + p2 ----
__global__ __launch_bounds__(256) void k_prep_p(const float* __restrict__ protos,
                                                unsigned short* __restrict__ pT,
                                                float* __restrict__ p2) {
  const int row = blockIdx.x;   // 2048
  const int tid = threadIdx.x;  // 256
  __shared__ float red[4];
  float s = 0.f;
  u16x8 h = (u16x8){0, 0, 0, 0, 0, 0, 0, 0};
  if (row < 2000) {
    const float* src = protos + (size_t)row * 2048 + tid * 8;
    f32x4 a = *(const f32x4*)src;
    f32x4 c = *(const f32x4*)(src + 4);
    h = (u16x8){f2bf(a.x), f2bf(a.y), f2bf(a.z), f2bf(a.w),
                f2bf(c.x), f2bf(c.y), f2bf(c.z), f2bf(c.w)};
    s = a.x * a.x + a.y * a.y + a.z * a.z + a.w * a.w +
        c.x * c.x + c.y * c.y + c.z * c.z + c.w * c.w;
  }
  *(u16x8*)(pT + (size_t)row * 2048 + tid * 8) = h;
  #pragma unroll
  for (int off = 32; off; off >>= 1) s += __shfl_xor(s, off);
  if ((tid & 63) == 0) red[tid >> 6] = s;
  __syncthreads();
  if (tid == 0) p2[row] = red[0] + red[1] + red[2] + red[3];
}

// ---- x (b,k,n) f32 -> xT[(b*196+n)*2048+k] bf16 + x2 partials ----
__global__ __launch_bounds__(256) void k_prep_x(const float* __restrict__ x,
                                                unsigned short* __restrict__ xT,
                                                float* __restrict__ x2p) {
  const int kt = blockIdx.x;  // 32
  const int b  = blockIdx.y;  // 32
  const int tid = threadIdx.x;
  __shared__ unsigned short Ls[64][201];
  const float* src = x + ((size_t)b * 2048 + (size_t)kt * 64) * 196;
  for (int idx = tid; idx < 64 * 196; idx += 256) {
    int kk = idx / 196, n = idx - kk * 196;
    Ls[kk][n] = f2bf(src[idx]);
  }
  __syncthreads();
  if (tid < 196) {  // x2 partial from bf16 values (column tid)
    float s = 0.f;
    #pragma unroll
    for (int j = 0; j < 64; ++j) {
      float v = __uint_as_float((unsigned int)Ls[j][tid] << 16);
      s += v * v;
    }
    x2p[kt * 6272 + b * 196 + tid] = s;
  }
  // coalesced u32 writes: consecutive tids -> consecutive j within a row
  unsigned short* dstb = xT + (size_t)b * 196 * 2048 + kt * 64;
  for (int idx = tid; idx < 196 * 32; idx += 256) {
    int n = idx >> 5, j = idx & 31;
    unsigned int v = (unsigned int)Ls[2 * j][n] |
                     ((unsigned int)Ls[2 * j + 1][n] << 16);
    *(unsigned int*)(dstb + (size_t)n * 2048 + 2 * j) = v;
  }
}

__global__ void k_x2r(const float* __restrict__ x2p, float* __restrict__ x2) {
  int i = blockIdx.x * blockDim.x + threadIdx.x;
  if (i >= 6272) return;
  float s = 0.f;
  #pragma unroll
  for (int c = 0; c < 32; ++c) s += x2p[c * 6272 + i];
  x2[i] = s;
}

// ---- main GEMM: 256x256 tile, BK=64, 8-wave, 8-phase counted-vmcnt ----
__global__ __launch_bounds__(512, 2) void k_main(
    const unsigned short* __restrict__ pT, const unsigned short* __restrict__ xT,
    const float* __restrict__ p2, const float* __restrict__ x2,
    unsigned int* __restrict__ outu) {
  // XCD swizzle: 200 blocks -> XCD x owns wgid [25x,25x+25): 2 ptiles x ~12.5 mtiles
  const int orig = blockIdx.x;
  const int wgid = (orig & 7) * 25 + (orig >> 3);
  const int ptpair = wgid / 50;
  const int rem = wgid - ptpair * 50;
  const int ptile = ptpair * 2 + (rem & 1);  // 0..7
  const int mtile = rem >> 1;                // 0..24
  const int p0 = ptile * 256;
  const int m0 = mtile * 256;
  const int tid = threadIdx.x;
  const int lane = tid & 63;
  const int w = tid >> 6;   // 8 waves
  const int wp = w >> 2;    // A half (128 rows)
  const int wn = w & 3;     // B quarter (64 rows)
  const int lr = lane & 15;
  const int lg = lane >> 4;

  __shared__ __align__(16) char S[131072];  // A[2]:0..64K, B[2]:64K..128K

  f32x4 acc[8][4];
  #pragma unroll
  for (int mi = 0; mi < 8; ++mi)
    #pragma unroll
    for (int ni = 0; ni < 4; ++ni)
      acc[mi][ni] = (f32x4){0.f, 0.f, 0.f, 0.f};

  // staging: linear LDS dest (uniform + lane*16), pre-swizzled global source
  const int rowbase = tid >> 3;                       // 0..63
  const int chunk = (tid & 7) ^ (rowbase & 7);        // involution
  const char* gA = (const char*)pT + (size_t)(p0 + rowbase) * 4096 + chunk * 16;
  const char* gB = (const char*)xT + (size_t)(m0 + rowbase) * 4096 + chunk * 16;
  const int wbase = w * 1024;

#define STAGE_A(c_, kt_, h_) do {                                              \
    const char* s_ = gA + (size_t)((h_) * 128 * 4096) + (size_t)(kt_) * 128;   \
    _Pragma("unroll")                                                          \
    for (int j_ = 0; j_ < 2; ++j_)                                             \
      __builtin_amdgcn_global_load_lds(                                        \
          (const AS1 void*)(s_ + (size_t)j_ * 64 * 4096),                      \
          (AS3 void*)(S + (c_) * 32768 + (h_) * 16384 + j_ * 8192 + wbase),    \
          16, 0, 0);                                                           \
  } while (0)
#define STAGE_B(c_, kt_, h_) do {                                              \
    const char* s_ = gB + (size_t)((h_) * 128 * 4096) + (size_t)(kt_) * 128;   \
    _Pragma("unroll")                                                          \
    for (int j_ = 0; j_ < 2; ++j_)                                             \
      __builtin_amdgcn_global_load_lds(                                        \
          (const AS1 void*)(s_ + (size_t)j_ * 64 * 4096),                      \
          (AS3 void*)(S + 65536 + (c_) * 32768 + (h_) * 16384 + j_ * 8192 + wbase), \
          16, 0, 0);                                                           \
  } while (0)

  // ds_read fragment bases (swizzle indep. of mi/ni since 16-row steps)
  const int swz = ((lr & 7) << 4);
  const int abase0 = (wp * 128 + lr) * 128 + ((lg * 16) ^ swz);
  const int abase1 = abase0 ^ 64;
  const int bbase0 = (wn * 64 + lr) * 128 + ((lg * 16) ^ swz);
  const int bbase1 = bbase0 ^ 64;

#define PH_BAR() do { __builtin_amdgcn_sched_barrier(0);                       \
    __builtin_amdgcn_s_barrier(); __builtin_amdgcn_sched_barrier(0); } while (0)
#define LGKM0() do { asm volatile("s_waitcnt lgkmcnt(0)" ::: "memory");        \
    __builtin_amdgcn_sched_barrier(0); } while (0)
#define MFMA_Q(mlo_, af_, bf_) do { __builtin_amdgcn_s_setprio(1);             \
    _Pragma("unroll")                                                          \
    for (int mi_ = (mlo_); mi_ < (mlo_) + 4; ++mi_)                            \
      _Pragma("unroll")                                                        \
      for (int ni_ = 0; ni_ < 4; ++ni_)                                        \
        acc[mi_][ni_] = __builtin_amdgcn_mfma_f32_16x16x32_bf16(               \
            af_[mi_], bf_[ni_], acc[mi_][ni_], 0, 0, 0);                       \
    __builtin_amdgcn_s_setprio(0); } while (0)

#define KT_BODY(kt_, c_) do {                                                  \
    bf16x8 a0[8], a1[8], b0[4], b1[4];                                         \
    /* P0: a-kh0 + b-kh0 reads; stage B[kt+1] */                               \
    _Pragma("unroll")                                                          \
    for (int mi_ = 0; mi_ < 8; ++mi_)                                          \
      a0[mi_] = *(const bf16x8*)(S + (c_) * 32768 + abase0 + mi_ * 2048);      \
    _Pragma("unroll")                                                          \
    for (int ni_ = 0; ni_ < 4; ++ni_)                                          \
      b0[ni_] = *(const bf16x8*)(S + 65536 + (c_) * 32768 + bbase0 + ni_ * 2048); \
    if ((kt_) + 1 < 32) { STAGE_B((c_) ^ 1, (kt_) + 1, 0); STAGE_B((c_) ^ 1, (kt_) + 1, 1); } \
    PH_BAR(); LGKM0();                                                         \
    MFMA_Q(0, a0, b0);                                                         \
    PH_BAR();                                                                  \
    /* P1: a-kh1 reads (prefetch) */                                           \
    _Pragma("unroll")                                                          \
    for (int mi_ = 0; mi_ < 8; ++mi_)                                          \
      a1[mi_] = *(const bf16x8*)(S + (c_) * 32768 + abase1 + mi_ * 2048);      \
    PH_BAR(); LGKM0();                                                         \
    MFMA_Q(4, a0, b0);                                                         \
    PH_BAR();                                                                  \
    /* P2: b-kh1 reads; stage A0[kt+2] */                                      \
    _Pragma("unroll")                                                          \
    for (int ni_ = 0; ni_ < 4; ++ni_)                                          \
      b1[ni_] = *(const bf16x8*)(S + 65536 + (c_) * 32768 + bbase1 + ni_ * 2048); \
    if ((kt_) + 2 < 32) STAGE_A((c_), (kt_) + 2, 0);                           \
    PH_BAR(); LGKM0();                                                         \
    MFMA_Q(0, a1, b1);                                                         \
    PH_BAR();                                                                  \
    /* P3: stage A1[kt+2]; counted vmcnt guards buf[kt+1] */                   \
    if ((kt_) + 2 < 32) STAGE_A((c_), (kt_) + 2, 1);                           \
    if ((kt_) < 30)       asm volatile("s_waitcnt vmcnt(4)" ::: "memory");     \
    else if ((kt_) == 30) asm volatile("s_waitcnt vmcnt(0)" ::: "memory");     \
    __builtin_amdgcn_sched_barrier(0);                                         \
    PH_BAR();                                                                  \
    MFMA_Q(4, a1, b1);                                                         \
    PH_BAR();                                                                  \
  } while (0)

  // prologue: buf0 (A0,A1,B0,B1) + buf1 A-halves; wait buf0; sync
  STAGE_A(0, 0, 0); STAGE_A(0, 0, 1);
  STAGE_B(0, 0, 0); STAGE_B(0, 0, 1);
  STAGE_A(1, 1, 0); STAGE_A(1, 1, 1);
  asm volatile("s_waitcnt vmcnt(4)" ::: "memory");
  __builtin_amdgcn_sched_barrier(0);
  __builtin_amdgcn_s_barrier();
  __builtin_amdgcn_sched_barrier(0);

  #pragma unroll 1
  for (int it = 0; it < 16; ++it) {
    KT_BODY(2 * it, 0);
    KT_BODY(2 * it + 1, 1);
  }
#undef KT_BODY
#undef MFMA_Q
#undef STAGE_A
#undef STAGE_B

  // epilogue: d2 = x2[m] + p2[p] - 2*dot ; per-wave 64-col window spans <=2 batches
  const int wm_base = m0 + wn * 64;
  const int b_lo = wm_base / 196;
  int b_hi = (wm_base + 63) / 196;
  if (b_hi > 31) b_hi = 31;
  const bool wave_ok = (b_lo < 32);
  float x2v[4];
  int seg0[4];
  #pragma unroll
  for (int ni = 0; ni < 4; ++ni) {
    const int m = wm_base + ni * 16 + lr;  // D col = lane&15
    x2v[ni] = x2[m];
    seg0[ni] = ((m / 196) == b_lo);
  }
  const float INF = __uint_as_float(INF_BITS);
  #pragma unroll
  for (int mi = 0; mi < 8; ++mi) {
    const int prow = p0 + wp * 128 + mi * 16 + 4 * lg;  // D row = 4*(lane>>4)+j
    #pragma unroll
    for (int j = 0; j < 4; ++j) {
      const int p = prow + j;
      const float pp = p2[p];
      float ma = INF, mb = INF;
      #pragma unroll
      for (int ni = 0; ni < 4; ++ni) {
        const float d2 = x2v[ni] + pp - 2.f * acc[mi][ni][j];
        ma = fminf(ma, seg0[ni] ? d2 : INF);
        mb = fminf(mb, seg0[ni] ? INF : d2);
      }
      #pragma unroll
      for (int off = 1; off < 16; off <<= 1) {
        ma = fminf(ma, __shfl_xor(ma, off));
        mb = fminf(mb, __shfl_xor(mb, off));
      }
      if (lr == 0 && p < 2000 && wave_ok) {
        atomicMin(&outu[6400 + b_lo * 2000 + p], __float_as_uint(fmaxf(ma, 0.f)));
        if (b_hi != b_lo)
          atomicMin(&outu[6400 + b_hi * 2000 + p], __float_as_uint(fmaxf(mb, 0.f)));
      }
    }
  }
}

// ---- post: d = sqrt(max(d2,1e-12)) in place; sim -> simbuf ----
__global__ void k_post(float* __restrict__ out, float* __restrict__ simbuf) {
  int i = blockIdx.x * blockDim.x + threadIdx.x;
  if (i >= 64000) return;
  float d2 = out[6400 + i];
  float d = sqrtf(fmaxf(d2, 1e-12f));
  out[6400 + i] = d;
  simbuf[i] = logf((d + 1.0f) / (d + 1e-7f));
}

// ---- scores: one wave per (b, class) pair ----
__global__ __launch_bounds__(256) void k_scores(const float* __restrict__ fc_w,
                                                const float* __restrict__ simbuf,
                                                float* __restrict__ out) {
  const int id = blockIdx.x * 4 + (threadIdx.x >> 6);  // 0..6399
  const int lane = threadIdx.x & 63;
  const int b = id / 200;
  const int c = id - b * 200;
  const f32x4* sv = (const f32x4*)(simbuf + (size_t)b * 2000);
  const f32x4* wv = (const f32x4*)(fc_w + (size_t)c * 2000);
  float s = 0.f;
  #pragma unroll
  for (int it = 0; it < 8; ++it) {
    int i = lane + it * 64;
    if (i < 500) {
      f32x4 a = sv[i], w4 = wv[i];
      s += a.x * w4.x + a.y * w4.y + a.z * w4.z + a.w * w4.w;
    }
  }
  #pragma unroll
  for (int off = 32; off; off >>= 1) s += __shfl_xor(s, off);
  if (lane == 0) out[b * 200 + c] = s;
}

extern "C" void kernel_launch(void* const* d_in, const int* in_sizes, int n_in,
                              void* d_out, int out_size, void* d_ws, size_t ws_size,
                              hipStream_t stream) {
  const float* x      = (const float*)d_in[0];  // (32, 2048, 14, 14) f32
  const float* protos = (const float*)d_in[1];  // (1, 2000, 2048) f32
  const float* fc_w   = (const float*)d_in[2];  // (200, 2000) f32
  float* out = (float*)d_out;                   // 6400 scores + 64000 min-dists

  char* wsb = (char*)d_ws;
  unsigned short* pT = (unsigned short*)wsb;              // 2048*4096B  = 8388608
  unsigned short* xT = (unsigned short*)(wsb + 8388608);  // 6400*4096B  = 26214400
  float* p2   = (float*)(wsb + 34603008);                 // 2048 f32
  float* x2   = (float*)(wsb + 34611200);                 // 6400 f32 (pad +inf)
  float* x2p  = (float*)(wsb + 34636800);                 // 32*6272 f32
  float* simb = (float*)(wsb + 34636800);                 // aliases x2p (used later)

  k_init<<<256, 256, 0, stream>>>((unsigned int*)d_out,
                                  (u32x4*)(wsb + 8388608 + (size_t)6272 * 4096),
                                  (unsigned int*)x2);
  k_prep_p<<<2048, 256, 0, stream>>>(protos, pT, p2);
  k_prep_x<<<dim3(32, 32), 256, 0, stream>>>(x, xT, x2p);
  k_x2r<<<25, 256, 0, stream>>>(x2p, x2);
  k_main<<<200, 512, 0, stream>>>(pT, xT, p2, x2, (unsigned int*)d_out);
  k_post<<<250, 256, 0, stream>>>(out, simb);
  k_scores<<<1600, 256, 0, stream>>>(fc_w, simb, out);
}

// Round 5
// 102.374 us; speedup vs baseline: 3.7277x; 1.3576x over previous
//
#include <hip/hip_runtime.h>

#define INF_BITS 0x7F800000u
#define AS1 __attribute__((address_space(1)))
#define AS3 __attribute__((address_space(3)))

typedef float f32x4 __attribute__((ext_vector_type(4)));
typedef __bf16 bf16x8 __attribute__((ext_vector_type(8)));
typedef unsigned short u16x8 __attribute__((ext_vector_type(8)));
typedef unsigned int u32x4 __attribute__((ext_vector_type(4)));

static __device__ __forceinline__ unsigned short f2bf(float f) {
  unsigned int u = __float_as_uint(f);
  return (unsigned short)((u + 0x7FFFu + ((u >> 16) & 1u)) >> 16);  // RTNE
}

// ---- init: +inf min-dists; zero xT pad rows; +inf x2 pad ----
__global__ void k_init(unsigned int* __restrict__ outu, u32x4* __restrict__ xTpad,
                       unsigned int* __restrict__ x2u) {
  int i = blockIdx.x * blockDim.x + threadIdx.x;
  if (i < 64000) outu[6400 + i] = INF_BITS;
  if (i < 32768) xTpad[i] = (u32x4){0u, 0u, 0u, 0u};  // rows 6272..6399 of xT
  if (i < 128) x2u[6272 + i] = INF_BITS;
}

// ---- protos (2000x2048 f32) -> pT (2048x2048 bf16, pad rows zero) + p2 ----
__global__ __launch_bounds__(256) void k_prep_p(const float* __restrict__ protos,
                                                unsigned short* __restrict__ pT,
                                                float* __restrict__ p2) {
  const int row = blockIdx.x;   // 2048
  const int tid = threadIdx.x;  // 256
  __shared__ float red[4];
  float s = 0.f;
  u16x8 h = (u16x8){0, 0, 0, 0, 0, 0, 0, 0};
  if (row < 2000) {
    const float* src = protos + (size_t)row * 2048 + tid * 8;
    f32x4 a = *(const f32x4*)src;
    f32x4 c = *(const f32x4*)(src + 4);
    h = (u16x8){f2bf(a.x), f2bf(a.y), f2bf(a.z), f2bf(a.w),
                f2bf(c.x), f2bf(c.y), f2bf(c.z), f2bf(c.w)};
    s = a.x * a.x + a.y * a.y + a.z * a.z + a.w * a.w +
        c.x * c.x + c.y * c.y + c.z * c.z + c.w * c.w;
  }
  *(u16x8*)(pT + (size_t)row * 2048 + tid * 8) = h;
  #pragma unroll
  for (int off = 32; off; off >>= 1) s += __shfl_xor(s, off);
  if ((tid & 63) == 0) red[tid >> 6] = s;
  __syncthreads();
  if (tid == 0) p2[row] = red[0] + red[1] + red[2] + red[3];
}

// ---- x (b,k,n) f32 -> xT[(b*196+n)*2048+k] bf16 + x2 partials ----
__global__ __launch_bounds__(256) void k_prep_x(const float* __restrict__ x,
                                                unsigned short* __restrict__ xT,
                                                float* __restrict__ x2p) {
  const int kt = blockIdx.x;  // 32
  const int b  = blockIdx.y;  // 32
  const int tid = threadIdx.x;
  __shared__ unsigned short Ls[64][201];
  const float* src = x + ((size_t)b * 2048 + (size_t)kt * 64) * 196;
  for (int idx = tid; idx < 64 * 196; idx += 256) {
    int kk = idx / 196, n = idx - kk * 196;
    Ls[kk][n] = f2bf(src[idx]);
  }
  __syncthreads();
  if (tid < 196) {  // x2 partial from bf16 values (column tid)
    float s = 0.f;
    #pragma unroll
    for (int j = 0; j < 64; ++j) {
      float v = __uint_as_float((unsigned int)Ls[j][tid] << 16);
      s += v * v;
    }
    x2p[kt * 6272 + b * 196 + tid] = s;
  }
  unsigned short* dstb = xT + (size_t)b * 196 * 2048 + kt * 64;
  for (int idx = tid; idx < 196 * 32; idx += 256) {
    int n = idx >> 5, j = idx & 31;
    unsigned int v = (unsigned int)Ls[2 * j][n] |
                     ((unsigned int)Ls[2 * j + 1][n] << 16);
    *(unsigned int*)(dstb + (size_t)n * 2048 + 2 * j) = v;
  }
}

__global__ void k_x2r(const float* __restrict__ x2p, float* __restrict__ x2) {
  int i = blockIdx.x * blockDim.x + threadIdx.x;
  if (i >= 6272) return;
  float s = 0.f;
  #pragma unroll
  for (int c = 0; c < 32; ++c) s += x2p[c * 6272 + i];
  x2[i] = s;
}

// ---- main GEMM: 256x256 tile, BK=64, 8 waves, m201-style 4-phase/K-tile ----
__global__ __launch_bounds__(512, 2) void k_main(
    const unsigned short* __restrict__ pT, const unsigned short* __restrict__ xT,
    const float* __restrict__ p2, const float* __restrict__ x2,
    unsigned int* __restrict__ outu) {
  // XCD swizzle: XCD x owns wgid [25x, 25x+25) = 2 ptiles x ~12.5 mtiles
  const int orig = blockIdx.x;
  const int wgid = (orig & 7) * 25 + (orig >> 3);
  const int ptpair = wgid / 50;
  const int rem = wgid - ptpair * 50;
  const int ptile = ptpair * 2 + (rem & 1);  // 0..7
  const int mtile = rem >> 1;                // 0..24
  const int p0 = ptile * 256;
  const int m0 = mtile * 256;
  const int tid = threadIdx.x;
  const int lane = tid & 63;
  const int w = tid >> 6;   // 8 waves
  const int wp = w >> 2;    // A half (128 rows)
  const int wn = w & 3;     // B quarter (64 rows)
  const int lr = lane & 15;
  const int lg = lane >> 4;

  __shared__ __align__(16) char S[131072];  // A[2]:0..64K, B[2]:64K..128K

  f32x4 acc[8][4];
  #pragma unroll
  for (int mi = 0; mi < 8; ++mi)
    #pragma unroll
    for (int ni = 0; ni < 4; ++ni)
      acc[mi][ni] = (f32x4){0.f, 0.f, 0.f, 0.f};

  // staging: linear LDS dest, pre-swizzled global source (chunk ^= row&7)
  const int rowbase = tid >> 3;                       // 0..63
  const int chunk = (tid & 7) ^ (rowbase & 7);        // involution
  const char* gA = (const char*)pT + (size_t)(p0 + rowbase) * 4096 + chunk * 16;
  const char* gB = (const char*)xT + (size_t)(m0 + rowbase) * 4096 + chunk * 16;
  const int wbase = w * 1024;

#define STAGE_A(c_, kt_, h_) do {                                              \
    const char* s_ = gA + (size_t)((h_) * 128 * 4096) + (size_t)(kt_) * 128;   \
    _Pragma("unroll")                                                          \
    for (int j_ = 0; j_ < 2; ++j_)                                             \
      __builtin_amdgcn_global_load_lds(                                        \
          (const AS1 void*)(s_ + (size_t)j_ * 64 * 4096),                      \
          (AS3 void*)(S + (c_) * 32768 + (h_) * 16384 + j_ * 8192 + wbase),    \
          16, 0, 0);                                                           \
  } while (0)
#define STAGE_B(c_, kt_, h_) do {                                              \
    const char* s_ = gB + (size_t)((h_) * 128 * 4096) + (size_t)(kt_) * 128;   \
    _Pragma("unroll")                                                          \
    for (int j_ = 0; j_ < 2; ++j_)                                             \
      __builtin_amdgcn_global_load_lds(                                        \
          (const AS1 void*)(s_ + (size_t)j_ * 64 * 4096),                      \
          (AS3 void*)(S + 65536 + (c_) * 32768 + (h_) * 16384 + j_ * 8192 + wbase), \
          16, 0, 0);                                                           \
  } while (0)

  // ds_read fragment addressing (row&7 == lr&7 since all row steps are x16)
  const int swz = ((lr & 7) << 4);
  const int arow = (wp * 128 + lr) * 128;        // + hf*8192 + mi*2048
  const int brow = (wn * 64 + lr) * 128;         // + ni*2048 (B region +65536)
  const int koff0 = (lg * 16) ^ swz;
  const int koff1 = (64 + lg * 16) ^ swz;

#define READ_A(dst_, c_, ko_, hf_)                                             \
    _Pragma("unroll")                                                          \
    for (int mi_ = 0; mi_ < 4; ++mi_)                                          \
      dst_[mi_] = *(const bf16x8*)(S + (c_) * 32768 + arow + (hf_) * 8192 +    \
                                   mi_ * 2048 + (ko_));
#define READ_B(dst_, c_, ko_)                                                  \
    _Pragma("unroll")                                                          \
    for (int ni_ = 0; ni_ < 4; ++ni_)                                          \
      dst_[ni_] = *(const bf16x8*)(S + 65536 + (c_) * 32768 + brow +           \
                                   ni_ * 2048 + (ko_));

#define PH_BAR() do { __builtin_amdgcn_sched_barrier(0);                       \
    __builtin_amdgcn_s_barrier(); __builtin_amdgcn_sched_barrier(0); } while (0)
#define LGKM0() do { asm volatile("s_waitcnt lgkmcnt(0)" ::: "memory");        \
    __builtin_amdgcn_sched_barrier(0); } while (0)
#define MFMA_Q(mlo_, af_, bf_) do { __builtin_amdgcn_s_setprio(1);             \
    _Pragma("unroll")                                                          \
    for (int mi_ = (mlo_); mi_ < (mlo_) + 4; ++mi_)                            \
      _Pragma("unroll")                                                        \
      for (int ni_ = 0; ni_ < 4; ++ni_)                                        \
        acc[mi_][ni_] = __builtin_amdgcn_mfma_f32_16x16x32_bf16(               \
            af_[mi_ - (mlo_)], bf_[ni_], acc[mi_][ni_], 0, 0, 0);              \
    __builtin_amdgcn_s_setprio(0); } while (0)

  // Per K-tile kt (buf c): 4 phases; stages: A[kt+1]h0, A[kt+1]h1, B[kt+2]h0,
  // B[kt+2]h1 (one half-tile/phase); single counted vmcnt(4) at Ph3 retires
  // exactly {B[kt+1], A[kt+1]}, leaves B[kt+2] in flight.  sa_/sb_/vm_ are
  // compile-time literals (tail peeled).
#define KT_BODY(kt_, c_, sa_, sb_, vm_) do {                                   \
    bf16x8 alo[4], ahi[4], bk0[4], bk1[4];                                     \
    /* Ph0: a_lo kh0 + b kh0 ; stage A[kt+1]h0 */                              \
    READ_A(alo, c_, koff0, 0);                                                 \
    READ_B(bk0, c_, koff0);                                                    \
    if (sa_) STAGE_A((c_) ^ 1, (kt_) + 1, 0);                                  \
    PH_BAR(); LGKM0();                                                         \
    MFMA_Q(0, alo, bk0);                                                       \
    PH_BAR();                                                                  \
    /* Ph1: a_hi kh0 + b kh1 ; stage A[kt+1]h1 */                              \
    READ_A(ahi, c_, koff0, 1);                                                 \
    READ_B(bk1, c_, koff1);                                                    \
    if (sa_) STAGE_A((c_) ^ 1, (kt_) + 1, 1);                                  \
    PH_BAR(); LGKM0();                                                         \
    MFMA_Q(4, ahi, bk0);                                                       \
    PH_BAR();                                                                  \
    /* Ph2: a_lo kh1 ; stage B[kt+2]h0 (buf c B reads all landed @Ph1) */      \
    READ_A(alo, c_, koff1, 0);                                                 \
    if (sb_) STAGE_B(c_, (kt_) + 2, 0);                                        \
    PH_BAR(); LGKM0();                                                         \
    MFMA_Q(0, alo, bk1);                                                       \
    PH_BAR();                                                                  \
    /* Ph3: a_hi kh1 ; stage B[kt+2]h1 ; counted vmcnt */                      \
    READ_A(ahi, c_, koff1, 1);                                                 \
    if (sb_) STAGE_B(c_, (kt_) + 2, 1);                                        \
    if ((vm_) == 4)      asm volatile("s_waitcnt vmcnt(4)" ::: "memory");      \
    else if ((vm_) == 0) asm volatile("s_waitcnt vmcnt(0)" ::: "memory");      \
    __builtin_amdgcn_sched_barrier(0);                                         \
    PH_BAR(); LGKM0();                                                         \
    MFMA_Q(4, ahi, bk1);                                                       \
    PH_BAR();                                                                  \
  } while (0)

  // prologue: B[0],A[0] -> buf0 ; B[1] -> buf1 ; retire B0+A0, keep B1 flying
  STAGE_B(0, 0, 0); STAGE_B(0, 0, 1);
  STAGE_A(0, 0, 0); STAGE_A(0, 0, 1);
  STAGE_B(1, 1, 0); STAGE_B(1, 1, 1);
  asm volatile("s_waitcnt vmcnt(4)" ::: "memory");
  __builtin_amdgcn_sched_barrier(0);
  __builtin_amdgcn_s_barrier();
  __builtin_amdgcn_sched_barrier(0);

  #pragma unroll 1
  for (int it = 0; it < 15; ++it) {
    KT_BODY(2 * it, 0, 1, 1, 4);
    KT_BODY(2 * it + 1, 1, 1, 1, 4);
  }
  KT_BODY(30, 0, 1, 0, 0);   // stages A[31]; no B[32]; drain all
  KT_BODY(31, 1, 0, 0, -1);  // pure compute
#undef KT_BODY
#undef MFMA_Q
#undef READ_A
#undef READ_B
#undef STAGE_A
#undef STAGE_B

  // epilogue: d2 = x2[m] + p2[p] - 2*dot ; per-wave 64-col window, <=2 batches
  const int wm_base = m0 + wn * 64;
  const int b_lo = wm_base / 196;
  int b_hi = (wm_base + 63) / 196;
  if (b_hi > 31) b_hi = 31;
  const bool wave_ok = (b_lo < 32);
  float x2v[4];
  int seg0[4];
  #pragma unroll
  for (int ni = 0; ni < 4; ++ni) {
    const int m = wm_base + ni * 16 + lr;  // D col = lane&15
    x2v[ni] = x2[m];
    seg0[ni] = ((m / 196) == b_lo);
  }
  const float INF = __uint_as_float(INF_BITS);
  #pragma unroll
  for (int mi = 0; mi < 8; ++mi) {
    const int prow = p0 + wp * 128 + mi * 16 + 4 * lg;  // D row = 4*(lane>>4)+j
    #pragma unroll
    for (int j = 0; j < 4; ++j) {
      const int p = prow + j;
      const float pp = p2[p];
      float ma = INF, mb = INF;
      #pragma unroll
      for (int ni = 0; ni < 4; ++ni) {
        const float d2 = x2v[ni] + pp - 2.f * acc[mi][ni][j];
        ma = fminf(ma, seg0[ni] ? d2 : INF);
        mb = fminf(mb, seg0[ni] ? INF : d2);
      }
      #pragma unroll
      for (int off = 1; off < 16; off <<= 1) {
        ma = fminf(ma, __shfl_xor(ma, off));
        mb = fminf(mb, __shfl_xor(mb, off));
      }
      if (lr == 0 && p < 2000 && wave_ok) {
        atomicMin(&outu[6400 + b_lo * 2000 + p], __float_as_uint(fmaxf(ma, 0.f)));
        if (b_hi != b_lo)
          atomicMin(&outu[6400 + b_hi * 2000 + p], __float_as_uint(fmaxf(mb, 0.f)));
      }
    }
  }
}

// ---- post: d = sqrt(max(d2,1e-12)) in place; sim -> simbuf ----
__global__ void k_post(float* __restrict__ out, float* __restrict__ simbuf) {
  int i = blockIdx.x * blockDim.x + threadIdx.x;
  if (i >= 64000) return;
  float d2 = out[6400 + i];
  float d = sqrtf(fmaxf(d2, 1e-12f));
  out[6400 + i] = d;
  simbuf[i] = logf((d + 1.0f) / (d + 1e-7f));
}

// ---- scores: one wave per (b, class) pair ----
__global__ __launch_bounds__(256) void k_scores(const float* __restrict__ fc_w,
                                                const float* __restrict__ simbuf,
                                                float* __restrict__ out) {
  const int id = blockIdx.x * 4 + (threadIdx.x >> 6);  // 0..6399
  const int lane = threadIdx.x & 63;
  const int b = id / 200;
  const int c = id - b * 200;
  const f32x4* sv = (const f32x4*)(simbuf + (size_t)b * 2000);
  const f32x4* wv = (const f32x4*)(fc_w + (size_t)c * 2000);
  float s = 0.f;
  #pragma unroll
  for (int it = 0; it < 8; ++it) {
    int i = lane + it * 64;
    if (i < 500) {
      f32x4 a = sv[i], w4 = wv[i];
      s += a.x * w4.x + a.y * w4.y + a.z * w4.z + a.w * w4.w;
    }
  }
  #pragma unroll
  for (int off = 32; off; off >>= 1) s += __shfl_xor(s, off);
  if (lane == 0) out[b * 200 + c] = s;
}

extern "C" void kernel_launch(void* const* d_in, const int* in_sizes, int n_in,
                              void* d_out, int out_size, void* d_ws, size_t ws_size,
                              hipStream_t stream) {
  const float* x      = (const float*)d_in[0];  // (32, 2048, 14, 14) f32
  const float* protos = (const float*)d_in[1];  // (1, 2000, 2048) f32
  const float* fc_w   = (const float*)d_in[2];  // (200, 2000) f32
  float* out = (float*)d_out;                   // 6400 scores + 64000 min-dists

  char* wsb = (char*)d_ws;
  unsigned short* pT = (unsigned short*)wsb;              // 2048*4096B  = 8388608
  unsigned short* xT = (unsigned short*)(wsb + 8388608);  // 6400*4096B  = 26214400
  float* p2   = (float*)(wsb + 34603008);                 // 2048 f32
  float* x2   = (float*)(wsb + 34611200);                 // 6400 f32 (pad +inf)
  float* x2p  = (float*)(wsb + 34636800);                 // 32*6272 f32
  float* simb = (float*)(wsb + 34636800);                 // aliases x2p (used later)

  k_init<<<256, 256, 0, stream>>>((unsigned int*)d_out,
                                  (u32x4*)(wsb + 8388608 + (size_t)6272 * 4096),
                                  (unsigned int*)x2);
  k_prep_p<<<2048, 256, 0, stream>>>(protos, pT, p2);
  k_prep_x<<<dim3(32, 32), 256, 0, stream>>>(x, xT, x2p);
  k_x2r<<<25, 256, 0, stream>>>(x2p, x2);
  k_main<<<200, 512, 0, stream>>>(pT, xT, p2, x2, (unsigned int*)d_out);
  k_post<<<250, 256, 0, stream>>>(out, simb);
  k_scores<<<1600, 256, 0, stream>>>(fc_w, simb, out);
}